// Round 8
// baseline (250.875 us; speedup 1.0000x reference)
//
#include <hip/hip_runtime.h>
#include <math.h>

#define NN 4096
#define DD 64
#define MM 266
#define MP 272
#define NORMZ 0.35355339059327379f   // 64^-0.25
#define RATIO 0.06131393394849658f   // 266^-0.5
#define EPSV 1e-4f
#define NEG_INF (-3.4e38f)
#define LSTR 72                       // LDS row stride in ushorts (144B, 16B aligned)
#define GSTR 320                      // gctxT row stride in ushorts

typedef __attribute__((ext_vector_type(8))) short bfrag;
typedef __attribute__((ext_vector_type(4))) float f32x4;

#define MFMA(a, b, c) __builtin_amdgcn_mfma_f32_16x16x32_bf16((a), (b), (c), 0, 0, 0)

__device__ inline ushort bf16rne(float x) {
    union { float f; unsigned u; } c; c.f = x;
    unsigned r = c.u + 0x7FFFu + ((c.u >> 16) & 1u);
    return (ushort)(r >> 16);
}
__device__ inline float bf2f(ushort h) {
    union { unsigned u; float f; } c; c.u = ((unsigned)h) << 16;
    return c.f;
}
__device__ inline void splitf(float x, ushort& h, ushort& l) {
    h = bf16rne(x);
    l = bf16rne(x - bf2f(h));
}
// pack 8 scaled floats (two float4) into split bf16 fragments
__device__ inline void pack8(const float4& a, const float4& b, bfrag& H, bfrag& L) {
    ushort h, l;
    splitf(a.x, h, l); H[0] = (short)h; L[0] = (short)l;
    splitf(a.y, h, l); H[1] = (short)h; L[1] = (short)l;
    splitf(a.z, h, l); H[2] = (short)h; L[2] = (short)l;
    splitf(a.w, h, l); H[3] = (short)h; L[3] = (short)l;
    splitf(b.x, h, l); H[4] = (short)h; L[4] = (short)l;
    splitf(b.y, h, l); H[5] = (short)h; L[5] = (short)l;
    splitf(b.z, h, l); H[6] = (short)h; L[6] = (short)l;
    splitf(b.w, h, l); H[7] = (short)h; L[7] = (short)l;
}

// ---------------------------------------------------------------------------
// proj split: proj fp32 [266][64] -> pH/pL bf16 [272][64] (rows >=266 zero)
// ---------------------------------------------------------------------------
__global__ void proj_split(const float* __restrict__ proj,
                           ushort* __restrict__ pH, ushort* __restrict__ pL)
{
    int i = (blockIdx.x * 256 + threadIdx.x) * 4;   // 17*256*4 = 17408 = 272*64
    int m = i >> 6;
    float4 x = (m < MM) ? *(const float4*)(proj + i) : make_float4(0.f, 0.f, 0.f, 0.f);
    ushort h0, l0, h1, l1, h2, l2, h3, l3;
    splitf(x.x, h0, l0); splitf(x.y, h1, l1); splitf(x.z, h2, l2); splitf(x.w, h3, l3);
    *(ushort4*)(pH + i) = make_ushort4(h0, h1, h2, h3);
    *(ushort4*)(pL + i) = make_ushort4(l0, l1, l2, l3);
}

// ===========================================================================
// k-pass v8: round-7 structure (256 threads, A-fragments direct from global,
// LSTR=72 plain) with two changes:
//  (1) vT staging via in-register 4x4 shfl transpose -> ushort4 vector
//      stores (replaces 32 scalar 16-way-conflict stores per subtile with
//      8 vector 8-way stores);
//  (2) ctx/kc partials accumulate via atomicAdd into per-head ctxA/kcA
//      (removes the 35.6MB ctxP round-trip through HBM).
// grid (16 nblocks, 32 heads).
// ===========================================================================
__launch_bounds__(256, 2)
__global__ void kpass(const float* __restrict__ kin, const float* __restrict__ vin,
                      const ushort* __restrict__ pjH, const ushort* __restrict__ pjL,
                      float* __restrict__ ctxA, float* __restrict__ kcA,
                      float* __restrict__ pmax, float* __restrict__ vsum)
{
    __shared__ ushort dataH[64 * LSTR], dataLo[64 * LSTR];  // uT buffer
    __shared__ ushort vTH[64 * LSTR], vTLo[64 * LSTR];      // [e][n]
    __shared__ ushort r2H[64 * LSTR], r2Lo[64 * LSTR];      // projL chunk [m_l][k]
    __shared__ float kcS[MP];
    __shared__ float redS[4];
    __shared__ float vredS[DD];

    const int t = threadIdx.x;
    const int w = t >> 6;
    const int lane = t & 63;
    const int l15 = lane & 15;
    const int q = lane >> 4;
    const int hd = blockIdx.y;
    const int nb = blockIdx.x;

    kcS[t] = 0.f;
    if (t < 16) kcS[256 + t] = 0.f;
    if (t < DD) vredS[t] = 0.f;

    const f32x4 zf = {0.f, 0.f, 0.f, 0.f};
    f32x4 cacc[4][4];
    f32x4 cacc4 = zf;
    #pragma unroll
    for (int c = 0; c < 4; ++c)
        #pragma unroll
        for (int e = 0; e < 4; ++e) cacc[c][e] = zf;
    float bmaxl = NEG_INF;
    float4 vacc = make_float4(0.f, 0.f, 0.f, 0.f);

    #pragma unroll 1
    for (int st = 0; st < 4; ++st) {
        const int n0 = (nb << 8) + (st << 6);
        __syncthreads();   // protect vT/uT restage vs last chunk's ctx readers

        // ---- stage vT: in-register 4x4 transpose across quad {l15, q} ----
        // lane q holds row n = w*4 + q + 16j, cols e0..e0+3 (e0 = 4*l15);
        // after transpose lane q holds col e = 4*l15+q, rows n_base..n_base+3.
        const float* vb = vin + ((size_t)hd * NN + n0) * DD;
        #pragma unroll
        for (int j = 0; j < 4; ++j) {
            int i = (t + (j << 8)) << 2;
            float4 x = *(const float4*)(vb + i);
            vacc.x += x.x; vacc.y += x.y; vacc.z += x.z; vacc.w += x.w;
            const bool qlo = (q < 2), qev = ((q & 1) == 0);
            float r0 = __shfl_xor(qlo ? x.z : x.x, 32);
            float r1 = __shfl_xor(qlo ? x.w : x.y, 32);
            float z0 = qlo ? x.x : r0;
            float z1 = qlo ? x.y : r1;
            float z2 = qlo ? r0 : x.z;
            float z3 = qlo ? r1 : x.w;
            float s0 = __shfl_xor(qev ? z1 : z0, 16);
            float s1 = __shfl_xor(qev ? z3 : z2, 16);
            float T0 = qev ? z0 : s0;
            float T1 = qev ? s0 : z1;
            float T2 = qev ? z2 : s1;
            float T3 = qev ? s1 : z3;
            const int e = (l15 << 2) + q;
            const int nb4 = (w << 2) + (j << 4);
            ushort h0, l0, h1, l1, h2, l2, h3, l3;
            splitf(T0, h0, l0); splitf(T1, h1, l1);
            splitf(T2, h2, l2); splitf(T3, h3, l3);
            *(ushort4*)&vTH[e * LSTR + nb4] = make_ushort4(h0, h1, h2, h3);
            *(ushort4*)&vTLo[e * LSTR + nb4] = make_ushort4(l0, l1, l2, l3);
        }

        // ---- A-fragments + diag, direct from global (no LDS round trip) ----
        const float* kb = kin + ((size_t)hd * NN + n0) * DD;
        const int row = (w << 4) + l15;
        float4 x0 = *(const float4*)(kb + (row << 6) + (q << 3));
        float4 x1 = *(const float4*)(kb + (row << 6) + (q << 3) + 4);
        float4 x2 = *(const float4*)(kb + (row << 6) + 32 + (q << 3));
        float4 x3 = *(const float4*)(kb + (row << 6) + 32 + (q << 3) + 4);
        x0.x *= NORMZ; x0.y *= NORMZ; x0.z *= NORMZ; x0.w *= NORMZ;
        x1.x *= NORMZ; x1.y *= NORMZ; x1.z *= NORMZ; x1.w *= NORMZ;
        x2.x *= NORMZ; x2.y *= NORMZ; x2.z *= NORMZ; x2.w *= NORMZ;
        x3.x *= NORMZ; x3.y *= NORMZ; x3.z *= NORMZ; x3.w *= NORMZ;
        float ss = x0.x*x0.x + x0.y*x0.y + x0.z*x0.z + x0.w*x0.w
                 + x1.x*x1.x + x1.y*x1.y + x1.z*x1.z + x1.w*x1.w
                 + x2.x*x2.x + x2.y*x2.y + x2.z*x2.z + x2.w*x2.w
                 + x3.x*x3.x + x3.y*x3.y + x3.z*x3.z + x3.w*x3.w;
        ss += __shfl_xor(ss, 16);
        ss += __shfl_xor(ss, 32);
        float dg[4];
        #pragma unroll
        for (int r = 0; r < 4; ++r) dg[r] = 0.5f * __shfl(ss, (q << 2) + r);
        bfrag aH[2], aL[2];
        pack8(x0, x1, aH[0], aL[0]);
        pack8(x2, x3, aH[1], aL[1]);
        __syncthreads();   // vT ready

        #pragma unroll
        for (int c = 0; c < 5; ++c) {
            const int mtiles = (c < 4) ? 4 : 1;
            const int m0 = c << 6;
            // stage projL chunk (r2)
            {
                const int tot = mtiles << 7;   // mtiles*16*64/8
                for (int idx = t; idx < tot; idx += 256) {
                    int i = idx << 3; int r = i >> 6, cc = i & 63;
                    *(uint4*)&r2H[r * LSTR + cc] = *(const uint4*)(pjH + ((m0 + r) << 6) + cc);
                    *(uint4*)&r2Lo[r * LSTR + cc] = *(const uint4*)(pjL + ((m0 + r) << 6) + cc);
                }
            }
            __syncthreads();   // B1: projL ready; prior ctx readers of uT done

            // dd MFMAs
            f32x4 dd4[4];
            #pragma unroll
            for (int mt = 0; mt < 4; ++mt) {
                if (mt >= mtiles) break;
                const int mrow = (mt << 4) + l15;
                bfrag bH0 = *(const bfrag*)&r2H[mrow * LSTR + (q << 3)];
                bfrag bH1 = *(const bfrag*)&r2H[mrow * LSTR + 32 + (q << 3)];
                bfrag bL0 = *(const bfrag*)&r2Lo[mrow * LSTR + (q << 3)];
                bfrag bL1 = *(const bfrag*)&r2Lo[mrow * LSTR + 32 + (q << 3)];
                f32x4 a = zf;
                a = MFMA(aH[0], bL0, a);
                a = MFMA(aH[1], bL1, a);
                a = MFMA(aL[0], bH0, a);
                a = MFMA(aL[1], bH1, a);
                a = MFMA(aH[0], bH0, a);
                a = MFMA(aH[1], bH1, a);
                dd4[mt] = a;
            }
            // exp + max + kc + scatter uT into data region
            #pragma unroll
            for (int mt = 0; mt < 4; ++mt) {
                if (mt >= mtiles) break;
                const int mg = m0 + (mt << 4) + l15;
                const bool valid = (mg < MM);
                ushort uh[4], ul[4];
                float csum = 0.f;
                #pragma unroll
                for (int reg = 0; reg < 4; ++reg) {
                    float dv = dd4[mt][reg];
                    float u = 0.f;
                    if (valid) {
                        bmaxl = fmaxf(bmaxl, dv);
                        u = __expf(dv - dg[reg]);
                    }
                    csum += u;
                    splitf(u, uh[reg], ul[reg]);
                }
                *(ushort4*)&dataH[((mt << 4) + l15) * LSTR + (w << 4) + (q << 2)] =
                    make_ushort4(uh[0], uh[1], uh[2], uh[3]);
                *(ushort4*)&dataLo[((mt << 4) + l15) * LSTR + (w << 4) + (q << 2)] =
                    make_ushort4(ul[0], ul[1], ul[2], ul[3]);
                csum += __shfl_xor(csum, 16);
                csum += __shfl_xor(csum, 32);
                if (q == 0) atomicAdd(&kcS[mg], csum);
            }
            __syncthreads();   // B2: uT complete

            // ctx MFMAs: D[m][e] += uT . v
            if (c < 4) {
                const int mrow = (w << 4) + l15;
                bfrag uH0 = *(const bfrag*)&dataH[mrow * LSTR + (q << 3)];
                bfrag uH1 = *(const bfrag*)&dataH[mrow * LSTR + 32 + (q << 3)];
                bfrag uL0 = *(const bfrag*)&dataLo[mrow * LSTR + (q << 3)];
                bfrag uL1 = *(const bfrag*)&dataLo[mrow * LSTR + 32 + (q << 3)];
                #pragma unroll
                for (int et = 0; et < 4; ++et) {
                    const int erow = (et << 4) + l15;
                    bfrag vH0 = *(const bfrag*)&vTH[erow * LSTR + (q << 3)];
                    bfrag vH1 = *(const bfrag*)&vTH[erow * LSTR + 32 + (q << 3)];
                    bfrag vL0 = *(const bfrag*)&vTLo[erow * LSTR + (q << 3)];
                    bfrag vL1 = *(const bfrag*)&vTLo[erow * LSTR + 32 + (q << 3)];
                    f32x4 a = cacc[c][et];
                    a = MFMA(uH0, vL0, a);
                    a = MFMA(uH1, vL1, a);
                    a = MFMA(uL0, vH0, a);
                    a = MFMA(uL1, vH1, a);
                    a = MFMA(uH0, vH0, a);
                    a = MFMA(uH1, vH1, a);
                    cacc[c][et] = a;
                }
            } else {
                const int mrow = l15;   // m-tile 16 uses rows 0..15 of uT buffer
                bfrag uH0 = *(const bfrag*)&dataH[mrow * LSTR + (q << 3)];
                bfrag uH1 = *(const bfrag*)&dataH[mrow * LSTR + 32 + (q << 3)];
                bfrag uL0 = *(const bfrag*)&dataLo[mrow * LSTR + (q << 3)];
                bfrag uL1 = *(const bfrag*)&dataLo[mrow * LSTR + 32 + (q << 3)];
                const int erow = (w << 4) + l15;   // wave w -> e-tile w
                bfrag vH0 = *(const bfrag*)&vTH[erow * LSTR + (q << 3)];
                bfrag vH1 = *(const bfrag*)&vTH[erow * LSTR + 32 + (q << 3)];
                bfrag vL0 = *(const bfrag*)&vTLo[erow * LSTR + (q << 3)];
                bfrag vL1 = *(const bfrag*)&vTLo[erow * LSTR + 32 + (q << 3)];
                f32x4 a = cacc4;
                a = MFMA(uH0, vL0, a);
                a = MFMA(uH1, vL1, a);
                a = MFMA(uL0, vH0, a);
                a = MFMA(uL1, vH1, a);
                a = MFMA(uH0, vH0, a);
                a = MFMA(uH1, vH1, a);
                cacc4 = a;
            }
        }
    }

    __syncthreads();
    // block dd-max + vsum LDS reduce
    {
        float bm = bmaxl;
        #pragma unroll
        for (int d = 1; d < 64; d <<= 1) bm = fmaxf(bm, __shfl_xor(bm, d));
        if (lane == 0) redS[w] = bm;
    }
    {
        const int e0 = (t << 2) & 63;
        atomicAdd(&vredS[e0 + 0], vacc.x);
        atomicAdd(&vredS[e0 + 1], vacc.y);
        atomicAdd(&vredS[e0 + 2], vacc.z);
        atomicAdd(&vredS[e0 + 3], vacc.w);
    }
    __syncthreads();
    if (t == 0) pmax[hd * 16 + nb] = fmaxf(fmaxf(redS[0], redS[1]), fmaxf(redS[2], redS[3]));
    if (t < DD) atomicAdd(&vsum[hd * DD + t], vredS[t]);
    // kc partial via atomics
    for (int m = t; m < MP; m += 256) atomicAdd(&kcA[hd * MP + m], kcS[m]);
    // ctx partial via atomics into per-head accumulator (2.2MB total)
    float* cp = ctxA + (size_t)hd * MP * DD;
    #pragma unroll
    for (int c = 0; c < 4; ++c) {
        const int mbase = (c << 6) + (w << 4) + (q << 2);
        #pragma unroll
        for (int et = 0; et < 4; ++et)
            #pragma unroll
            for (int reg = 0; reg < 4; ++reg)
                atomicAdd(&cp[(mbase + reg) * DD + (et << 4) + l15], cacc[c][et][reg]);
    }
    #pragma unroll
    for (int reg = 0; reg < 4; ++reg)
        atomicAdd(&cp[(256 + (q << 2) + reg) * DD + (w << 4) + l15], cacc4[reg]);
}

// ===========================================================================
// ctx reduce: reduce the 512-entry pmax in-block, read the pre-accumulated
// ctxA/kcA (atomics in kpass replaced the 35.6MB partial spill), scale by
// Asc=RATIO*e^-stab, add REPS*vsum, split to bf16, write TRANSPOSED
// gctxT[hd][e][m] (64 e-rows/head), and write kcF as FLOAT.
// grid (17 m-tiles, 32 heads)
// ===========================================================================
__global__ void ctx_reduce(const float* __restrict__ ctxA, const float* __restrict__ kcA,
                           const float* __restrict__ vsum, const float* __restrict__ pmax,
                           ushort* __restrict__ gH, ushort* __restrict__ gL,
                           float* __restrict__ kcF)
{
    __shared__ ushort hiT[64][20], loT[64][20];
    __shared__ float rmxS[4];
    const int t = threadIdx.x, mt = blockIdx.x, hd = blockIdx.y;
    const int lane = t & 63, w = t >> 6;
    float mxl = fmaxf(pmax[t], pmax[t + 256]);
    #pragma unroll
    for (int d = 1; d < 64; d <<= 1) mxl = fmaxf(mxl, __shfl_xor(mxl, d));
    if (lane == 0) rmxS[w] = mxl;
    __syncthreads();
    const float stab = fmaxf(fmaxf(rmxS[0], rmxS[1]), fmaxf(rmxS[2], rmxS[3]));
    const float Asc = RATIO * __expf(-stab);
    const float REPS = RATIO * EPSV;
    const int e = t & 63, mq = t >> 6;
    const float vs = vsum[hd * DD + e];
    #pragma unroll
    for (int i = 0; i < 4; ++i) {
        const int ml = mq * 4 + i;
        const int m = mt * 16 + ml;
        float s = ctxA[((size_t)hd * MP + m) * DD + e];
        float val = Asc * s + REPS * vs;
        ushort h, l; splitf(val, h, l);
        hiT[e][ml] = h; loT[e][ml] = l;
    }
    __syncthreads();
    {
        const int i = t * 4, e2 = i >> 4, cc = i & 15;
        ushort4 hv = make_ushort4(hiT[e2][cc], hiT[e2][cc + 1], hiT[e2][cc + 2], hiT[e2][cc + 3]);
        ushort4 lv = make_ushort4(loT[e2][cc], loT[e2][cc + 1], loT[e2][cc + 2], loT[e2][cc + 3]);
        *(ushort4*)(gH + ((size_t)hd * 64 + e2) * GSTR + mt * 16 + cc) = hv;
        *(ushort4*)(gL + ((size_t)hd * 64 + e2) * GSTR + mt * 16 + cc) = lv;
    }
    if (t < 16) {
        const int m = mt * 16 + t;
        kcF[hd * MP + m] = Asc * kcA[hd * MP + m] + ((m < MM) ? REPS * (float)NN : 0.f);
    }
}

// ===========================================================================
// q-pass (round-2 v3, unchanged): A-fragments + diag direct from global;
// phase 1: proj chunks LDS-staged, dd via MFMA; phase 2: rowmax + qp + VALU
// denominator; phase 3: qp scatter + ctxT chunks staged, out MFMAs.
// LDS 36.9 KB -> 4 blocks/CU.  grid (64 nblocks, 32 heads), block 256.
// ===========================================================================
__launch_bounds__(256, 4)
__global__ void qpass(const float* __restrict__ qin,
                      const ushort* __restrict__ pjH, const ushort* __restrict__ pjL,
                      const ushort* __restrict__ gH, const ushort* __restrict__ gL,
                      const float* __restrict__ kcF,
                      float* __restrict__ outp)
{
    __shared__ ushort bPH[64 * LSTR], bPL[64 * LSTR];   // proj chunk, then qpA
    __shared__ ushort bQH[64 * LSTR], bQL[64 * LSTR];   // ctxT chunk

    const int t = threadIdx.x;
    const int w = t >> 6;
    const int lane = t & 63;
    const int l15 = lane & 15;
    const int q = lane >> 4;
    const int hd = blockIdx.y;
    const int n0 = blockIdx.x << 6;

    const float* qb = qin + ((size_t)hd * NN + n0) * DD;
    const int row = (w << 4) + l15;
    float4 x0 = *(const float4*)(qb + (row << 6) + (q << 3));
    float4 x1 = *(const float4*)(qb + (row << 6) + (q << 3) + 4);
    float4 x2 = *(const float4*)(qb + (row << 6) + 32 + (q << 3));
    float4 x3 = *(const float4*)(qb + (row << 6) + 32 + (q << 3) + 4);
    x0.x *= NORMZ; x0.y *= NORMZ; x0.z *= NORMZ; x0.w *= NORMZ;
    x1.x *= NORMZ; x1.y *= NORMZ; x1.z *= NORMZ; x1.w *= NORMZ;
    x2.x *= NORMZ; x2.y *= NORMZ; x2.z *= NORMZ; x2.w *= NORMZ;
    x3.x *= NORMZ; x3.y *= NORMZ; x3.z *= NORMZ; x3.w *= NORMZ;
    float ss = x0.x*x0.x + x0.y*x0.y + x0.z*x0.z + x0.w*x0.w
             + x1.x*x1.x + x1.y*x1.y + x1.z*x1.z + x1.w*x1.w
             + x2.x*x2.x + x2.y*x2.y + x2.z*x2.z + x2.w*x2.w
             + x3.x*x3.x + x3.y*x3.y + x3.z*x3.z + x3.w*x3.w;
    ss += __shfl_xor(ss, 16);
    ss += __shfl_xor(ss, 32);
    float dg[4];
    #pragma unroll
    for (int r = 0; r < 4; ++r) dg[r] = 0.5f * __shfl(ss, (q << 2) + r);
    bfrag aH[2], aL[2];
    pack8(x0, x1, aH[0], aL[0]);
    pack8(x2, x3, aH[1], aL[1]);

    const f32x4 zf = {0.f, 0.f, 0.f, 0.f};
    f32x4 ddq[17];

    // ---- phase 1: dd for all 272 m (proj chunks via LDS) ----
    #pragma unroll
    for (int c = 0; c < 5; ++c) {
        const int mtiles = (c < 4) ? 4 : 1;
        const int m0 = c << 6;
        __syncthreads();
        {
            const int tot = mtiles << 7;
            for (int idx = t; idx < tot; idx += 256) {
                int i = idx << 3; int r = i >> 6, cc = i & 63;
                *(uint4*)&bPH[r * LSTR + cc] = *(const uint4*)(pjH + ((m0 + r) << 6) + cc);
                *(uint4*)&bPL[r * LSTR + cc] = *(const uint4*)(pjL + ((m0 + r) << 6) + cc);
            }
        }
        __syncthreads();
        #pragma unroll
        for (int mt = 0; mt < 4; ++mt) {
            if (mt >= mtiles) break;
            const int mrow = (mt << 4) + l15;
            bfrag bH0 = *(const bfrag*)&bPH[mrow * LSTR + (q << 3)];
            bfrag bH1 = *(const bfrag*)&bPH[mrow * LSTR + 32 + (q << 3)];
            bfrag bL0 = *(const bfrag*)&bPL[mrow * LSTR + (q << 3)];
            bfrag bL1 = *(const bfrag*)&bPL[mrow * LSTR + 32 + (q << 3)];
            f32x4 a = zf;
            a = MFMA(aH[0], bL0, a);
            a = MFMA(aH[1], bL1, a);
            a = MFMA(aL[0], bH0, a);
            a = MFMA(aL[1], bH1, a);
            a = MFMA(aH[0], bH0, a);
            a = MFMA(aH[1], bH1, a);
            ddq[c * 4 + mt] = a;
        }
    }

    // ---- phase 2: rowmax + qp + denominator (registers only) ----
    float rmax[4];
    #pragma unroll
    for (int reg = 0; reg < 4; ++reg) {
        float mx = NEG_INF;
        #pragma unroll
        for (int ti = 0; ti < 17; ++ti) {
            bool valid = (ti < 16) || (l15 < 10);
            if (valid) mx = fmaxf(mx, ddq[ti][reg]);
        }
        #pragma unroll
        for (int d = 1; d < 16; d <<= 1) mx = fmaxf(mx, __shfl_xor(mx, d));
        rmax[reg] = mx;
    }
    #pragma unroll
    for (int ti = 0; ti < 17; ++ti) {
        #pragma unroll
        for (int reg = 0; reg < 4; ++reg) {
            bool valid = (ti < 16) || (l15 < 10);
            float e = 0.f;
            if (valid)
                e = RATIO * (__expf(ddq[ti][reg] - dg[reg] - rmax[reg]) + EPSV);
            ddq[ti][reg] = e;
        }
    }
    float dinv[4];
    {
        const float* kcb = kcF + hd * MP;
        float den[4] = {0.f, 0.f, 0.f, 0.f};
        #pragma unroll
        for (int ti = 0; ti < 17; ++ti) {
            float kv = kcb[(ti << 4) + l15];
            #pragma unroll
            for (int reg = 0; reg < 4; ++reg) den[reg] += ddq[ti][reg] * kv;
        }
        #pragma unroll
        for (int reg = 0; reg < 4; ++reg) {
            #pragma unroll
            for (int d = 1; d < 16; d <<= 1) den[reg] += __shfl_xor(den[reg], d);
            dinv[reg] = 1.f / den[reg];
        }
    }

    // ---- phase 3: out = qp @ ctxT (qp chunk in bufP, ctxT chunk in bufQ) ----
    f32x4 oacc[4];
    #pragma unroll
    for (int et = 0; et < 4; ++et) oacc[et] = zf;

    #pragma unroll
    for (int c = 0; c < 5; ++c) {
        const int mtiles = (c < 4) ? 4 : 1;
        __syncthreads();
        #pragma unroll
        for (int mt = 0; mt < 4; ++mt) {
            if (mt >= mtiles) break;
            const int ml = (mt << 4) + l15;
            #pragma unroll
            for (int reg = 0; reg < 4; ++reg) {
                ushort hh, ll; splitf(ddq[c * 4 + mt][reg], hh, ll);
                bPH[((w << 4) + (q << 2) + reg) * LSTR + ml] = hh;
                bPL[((w << 4) + (q << 2) + reg) * LSTR + ml] = ll;
            }
        }
        if (c == 4) {
            const int rown = (w << 4) + l15;
            *(ushort4*)&bPH[rown * LSTR + 16 + (q << 2)] = make_ushort4(0, 0, 0, 0);
            *(ushort4*)&bPL[rown * LSTR + 16 + (q << 2)] = make_ushort4(0, 0, 0, 0);
        }
        {
            for (int idx = t; idx < 512; idx += 256) {
                int i = idx << 3; int e = i >> 6, mm = i & 63;
                *(uint4*)&bQH[e * LSTR + mm] =
                    *(const uint4*)(gH + ((size_t)hd * 64 + e) * GSTR + (c << 6) + mm);
                *(uint4*)&bQL[e * LSTR + mm] =
                    *(const uint4*)(gL + ((size_t)hd * 64 + e) * GSTR + (c << 6) + mm);
            }
        }
        __syncthreads();
        const int arow = (w << 4) + l15;
        bfrag pH0 = *(const bfrag*)&bPH[arow * LSTR + (q << 3)];
        bfrag pL0 = *(const bfrag*)&bPL[arow * LSTR + (q << 3)];
        bfrag pH1, pL1;
        if (c < 4) {
            pH1 = *(const bfrag*)&bPH[arow * LSTR + 32 + (q << 3)];
            pL1 = *(const bfrag*)&bPL[arow * LSTR + 32 + (q << 3)];
        }
        #pragma unroll
        for (int et = 0; et < 4; ++et) {
            const int erow = (et << 4) + l15;
            bfrag cH0 = *(const bfrag*)&bQH[erow * LSTR + (q << 3)];
            bfrag cL0 = *(const bfrag*)&bQL[erow * LSTR + (q << 3)];
            f32x4 a = oacc[et];
            a = MFMA(pH0, cL0, a);
            a = MFMA(pL0, cH0, a);
            a = MFMA(pH0, cH0, a);
            if (c < 4) {
                bfrag cH1 = *(const bfrag*)&bQH[erow * LSTR + 32 + (q << 3)];
                bfrag cL1 = *(const bfrag*)&bQL[erow * LSTR + 32 + (q << 3)];
                a = MFMA(pH1, cL1, a);
                a = MFMA(pL1, cH1, a);
                a = MFMA(pH1, cH1, a);
            }
            oacc[et] = a;
        }
    }

    float* ob = outp + ((size_t)hd * NN + n0) * DD;
    #pragma unroll
    for (int et = 0; et < 4; ++et)
        #pragma unroll
        for (int reg = 0; reg < 4; ++reg)
            ob[((w << 4) + (q << 2) + reg) * DD + (et << 4) + l15] = oacc[et][reg] * dinv[reg];
}

// ---------------------------------------------------------------------------
extern "C" void kernel_launch(void* const* d_in, const int* in_sizes, int n_in,
                              void* d_out, int out_size, void* d_ws, size_t ws_size,
                              hipStream_t stream)
{
    const float* q = (const float*)d_in[0];
    const float* k = (const float*)d_in[1];
    const float* v = (const float*)d_in[2];
    const float* proj = (const float*)d_in[3];
    float* out = (float*)d_out;
    char* ws = (char*)d_ws;

    // zeroed region (memset below): gH, gL, vsum, ctxA, kcA
    ushort* gH  = (ushort*)(ws);                    // 32*64*320*2 = 1,310,720 B
    ushort* gL  = (ushort*)(ws + 1310720);          // 1,310,720 B
    float*  vsm = (float*)(ws + 2621440);           // 8,192 B
    float*  ctxA= (float*)(ws + 2629632);           // 32*272*64*4 = 2,228,224 B
    float*  kcA = (float*)(ws + 4857856);           // 34,816 B
    // non-zeroed
    ushort* pH  = (ushort*)(ws + 4892672);          // 34,816 B
    ushort* pL  = (ushort*)(ws + 4927488);          // 34,816 B
    float*  kcF = (float*)(ws + 4962304);           // 34,816 B
    float*  pmax= (float*)(ws + 4997120);           // 2,048 B

    hipMemsetAsync(ws, 0, 4892672, stream);         // gH, gL, vsum, ctxA, kcA

    proj_split<<<dim3(17), 256, 0, stream>>>(proj, pH, pL);
    kpass<<<dim3(16, 32), 256, 0, stream>>>(k, v, pH, pL, ctxA, kcA, pmax, vsm);
    ctx_reduce<<<dim3(17, 32), 256, 0, stream>>>(ctxA, kcA, vsm, pmax, gH, gL, kcF);
    qpass<<<dim3(64, 32), 256, 0, stream>>>(q, pH, pL, gH, gL, kcF, out);
}